// Round 9
// baseline (90.926 us; speedup 1.0000x reference)
//
#include <hip/hip_runtime.h>
#include <hip/hip_bf16.h>
#include <math.h>

// Problem constants (fixed by setup_inputs)
#define B_ 4
#define L_ 8192
#define M_ 4096
#define D_ 1024
#define CHUNK_ 32
#define NCC_ 128        // M_/CHUNK_
#define EPS_ 1e-4f

// Round-to-nearest-even f32 -> bf16 -> f32 (values are finite here)
__device__ __forceinline__ float bf16rf(float x) {
  unsigned u = __float_as_uint(x);
  u += 0x7FFFu + ((u >> 16) & 1u);
  u &= 0xFFFF0000u;
  return __uint_as_float(u);
}
// RNE f32 -> bf16 bits
__device__ __forceinline__ unsigned short bf16bits(float x) {
  unsigned u = __float_as_uint(x);
  u += 0x7FFFu + ((u >> 16) & 1u);
  return (unsigned short)(u >> 16);
}

// boundary_mask may arrive as bool8 (fmt 0), int32 (fmt 1), or float32 (fmt 2)
__device__ __forceinline__ bool mask_at(const void* mb, int fmt, int i) {
  if (fmt == 0) return ((const unsigned char*)mb)[i] != 0;
  if (fmt == 1) return ((const int*)mb)[i] != 0;
  return ((const float*)mb)[i] != 0.0f;
}

// prep: one 1024-thread block per batch; wave-level prefix scan (R8-proven).
__global__ void __launch_bounds__(1024)
k_prep(const float* __restrict__ bprob,
       const void* __restrict__ bmask,
       float4* __restrict__ scal,
       int* __restrict__ rowstart) {
  const int b = blockIdx.x;
  const int tid = threadIdx.x;  // 0..1023
  const int lane = tid & 63, wid = tid >> 6;
  __shared__ int s_flags[2];
  __shared__ int s_wsum[17];
  __shared__ float s_p[M_];

  if (tid < 2) s_flags[tid] = 0;
  __syncthreads();
  {
    const unsigned* mw = (const unsigned*)bmask;
    unsigned f0 = 0, f1 = 0;
    for (int i = tid; i < 8192; i += 1024) {
      unsigned v = mw[i];
      f0 |= v & 0xFFu;
      f1 |= v & 0xFF00u;
    }
    if (f1) s_flags[0] = 1;
    if (f0) s_flags[1] = 1;
  }
  __syncthreads();
  const int fmt = s_flags[0] ? 0 : (s_flags[1] ? 1 : 2);

  const int base_l = tid * (L_ / 1024);
  bool mloc[L_ / 1024];
  int cnt = 0;
#pragma unroll
  for (int j = 0; j < L_ / 1024; ++j) {
    mloc[j] = mask_at(bmask, fmt, b * L_ + base_l + j);
    cnt += mloc[j] ? 1 : 0;
  }
  int incl = cnt;
#pragma unroll
  for (int off = 1; off < 64; off <<= 1) {
    int t = __shfl_up(incl, off);
    if (lane >= off) incl += t;
  }
  if (lane == 63) s_wsum[wid] = incl;
  __syncthreads();
  if (tid == 0) {
    int acc = 0;
#pragma unroll
    for (int w = 0; w < 16; ++w) { int t = s_wsum[w]; s_wsum[w] = acc; acc += t; }
    s_wsum[16] = acc;
  }
  for (int r = tid; r <= M_; r += 1024) rowstart[b * (M_ + 1) + r] = L_;
  __syncthreads();
  const int excl = s_wsum[wid] + incl - cnt;
  const int nb = s_wsum[16];

  int run = excl;
#pragma unroll
  for (int j = 0; j < L_ / 1024; ++j) {
    int l = base_l + j;
    bool mb = mloc[j];
    int pos = mb ? run : (nb + (l - run));
    run += mb ? 1 : 0;
    if (pos < M_) {
      s_p[pos] = bprob[((size_t)(b * L_ + l)) * 2 + 1];
      if (mb) rowstart[b * (M_ + 1) + pos] = l;
    }
  }
  __syncthreads();

#pragma unroll
  for (int i = 0; i < M_ / 1024; ++i) {
    int m = i * 1024 + tid;
    float p = s_p[m];
    p = fminf(fmaxf(p, EPS_), 1.0f - EPS_);
    float dtf = bf16rf(logf(1.0f / (1.0f - p)));
    float a = expf(-dtf);
    scal[b * M_ + m] = make_float4(a, dtf * p, 1.0f / dtf, 0.0f);
  }
}

// Pass A: local chunk scan; hidden read ONCE here. Emits per-m local states
// as bf16 (stateL), per-m cumulative decay (cumA), chunk-end f32 partial
// (carry) and chunk decay product (Achunk).
__global__ void __launch_bounds__(256)
k_scanA(const float* __restrict__ hidden,
        const float4* __restrict__ scal,
        const int* __restrict__ rowstart,
        unsigned short* __restrict__ stateL,  // [B][M][D] bf16
        float* __restrict__ cumA,             // [B][M]
        float* __restrict__ carry,            // [B][NCC][D]
        float* __restrict__ Achunk) {         // [B][NCC]
  const int c = blockIdx.x, b = blockIdx.y;
  const int tid = threadIdx.x;
  if (rowstart[b * (M_ + 1) + c * CHUNK_] >= L_) return;  // inactive chunk
  __shared__ float4 s_scal[CHUNK_];
  __shared__ float  s_cumA[CHUNK_];
  if (tid < CHUNK_) s_scal[tid] = scal[b * M_ + c * CHUNK_ + tid];
  __syncthreads();
  if (tid == 0) {
    float cp = 1.0f;
#pragma unroll
    for (int m = 0; m < CHUNK_; ++m) { cp *= s_scal[m].x; s_cumA[m] = cp; }
    Achunk[b * NCC_ + c] = cp;
  }
  __syncthreads();
  if (tid < CHUNK_) cumA[b * M_ + c * CHUNK_ + tid] = s_cumA[tid];

  const int d4 = tid * 4;
  const float* __restrict__ hp =
      hidden + ((size_t)(b * M_ + c * CHUNK_)) * D_ + d4;
  unsigned short* __restrict__ slp =
      stateL + ((size_t)(b * M_ + c * CHUNK_)) * D_ + d4;
  float hx = 0.f, hy = 0.f, hz = 0.f, hw = 0.f;
#pragma unroll
  for (int m = 0; m < CHUNK_; ++m) {
    const float4 s = s_scal[m];                 // a, c=dt*p, 1/dt
    const float4 x = *(const float4*)(hp + (size_t)m * D_);
    hx = fmaf(s.x, hx, s.y * bf16rf(x.x * s.z));
    hy = fmaf(s.x, hy, s.y * bf16rf(x.y * s.z));
    hz = fmaf(s.x, hz, s.y * bf16rf(x.z * s.z));
    hw = fmaf(s.x, hw, s.y * bf16rf(x.w * s.z));
    ushort4 st;
    st.x = bf16bits(hx); st.y = bf16bits(hy);
    st.z = bf16bits(hz); st.w = bf16bits(hw);
    *(ushort4*)(slp + (size_t)m * D_) = st;
  }
  *(float4*)(carry + ((size_t)(b * NCC_ + c)) * D_ + d4) =
      make_float4(hx, hy, hz, hw);
}

// Pass B: in-place inclusive scan across chunks (R8-proven, batch-16).
__global__ void __launch_bounds__(64)
k_scanB(float* __restrict__ carry, const float* __restrict__ Achunk) {
  const int chain = blockIdx.x * 64 + threadIdx.x;  // 0..4095
  const int bb = chain >> 10, dd = chain & 1023;
  const float* __restrict__ Ab = Achunk + bb * NCC_;
  float S = 0.0f;
  for (int g = 0; g < NCC_ / 16; ++g) {
    float v[16], A[16];
#pragma unroll
    for (int j = 0; j < 16; ++j)
      v[j] = carry[((size_t)(bb * NCC_ + g * 16 + j)) * D_ + dd];
#pragma unroll
    for (int j = 0; j < 16; ++j) A[j] = Ab[g * 16 + j];
#pragma unroll
    for (int j = 0; j < 16; ++j) { S = fmaf(A[j], S, v[j]); v[j] = S; }
#pragma unroll
    for (int j = 0; j < 16; ++j)
      carry[((size_t)(bb * NCC_ + g * 16 + j)) * D_ + dd] = v[j];
  }
}

// Pass C: pure streaming finalize + scatter. No serial chain: every m is
// independent -> out = bf16rf(ci*cumA[m] + f32(stateL[m])).
__global__ void __launch_bounds__(256)
k_scanC(const unsigned short* __restrict__ stateL,
        const float* __restrict__ cumA,
        const int* __restrict__ rowstart,
        const float* __restrict__ carry,
        float* __restrict__ out) {
  const int c = blockIdx.x, b = blockIdx.y;
  const int tid = threadIdx.x;
  __shared__ float s_cumA[CHUNK_];
  __shared__ int   s_rs[CHUNK_ + 1];
  if (tid < CHUNK_)  s_cumA[tid] = cumA[b * M_ + c * CHUNK_ + tid];
  if (tid <= CHUNK_) s_rs[tid]   = rowstart[b * (M_ + 1) + c * CHUNK_ + tid];
  __syncthreads();
  if (s_rs[0] >= L_) return;                    // inactive chunk
  const int d4 = tid * 4;
  float cix = 0.f, ciy = 0.f, ciz = 0.f, ciw = 0.f;
  if (c > 0) {
    const float4 ci =
        *(const float4*)(carry + ((size_t)(b * NCC_ + c - 1)) * D_ + d4);
    cix = ci.x; ciy = ci.y; ciz = ci.z; ciw = ci.w;
  }
  const unsigned short* __restrict__ slp =
      stateL + ((size_t)(b * M_ + c * CHUNK_)) * D_ + d4;
#pragma unroll
  for (int m = 0; m < CHUNK_; ++m) {
    const int r0 = s_rs[m], r1 = s_rs[m + 1];
    if (r1 > r0) {
      const ushort4 st = *(const ushort4*)(slp + (size_t)m * D_);
      const float cA = s_cumA[m];
      float4 o;
      o.x = bf16rf(fmaf(cix, cA, __uint_as_float((unsigned)st.x << 16)));
      o.y = bf16rf(fmaf(ciy, cA, __uint_as_float((unsigned)st.y << 16)));
      o.z = bf16rf(fmaf(ciz, cA, __uint_as_float((unsigned)st.z << 16)));
      o.w = bf16rf(fmaf(ciw, cA, __uint_as_float((unsigned)st.w << 16)));
      for (int l = r0; l < r1; ++l)
        *(float4*)(out + ((size_t)(b * L_ + l)) * D_ + d4) = o;
    }
  }
}

extern "C" void kernel_launch(void* const* d_in, const int* in_sizes, int n_in,
                              void* d_out, int out_size, void* d_ws, size_t ws_size,
                              hipStream_t stream) {
  const float* hidden = (const float*)d_in[0];
  const float* bprob  = (const float*)d_in[1];
  const void*  bmask  = d_in[2];
  float* out = (float*)d_out;

  float4*         scal    = (float4*)d_ws;                        // B*M float4
  float*          carry   = (float*)(scal + B_ * M_);             // B*NCC*D
  float*          Achunk  = carry + (size_t)B_ * NCC_ * D_;       // B*NCC
  float*          cumA    = Achunk + B_ * NCC_;                   // B*M
  int*            rowstart = (int*)(cumA + B_ * M_);              // B*(M+1)
  unsigned short* stateL  = (unsigned short*)(rowstart + B_ * (M_ + 1)); // B*M*D bf16

  k_prep<<<dim3(B_), dim3(1024), 0, stream>>>(bprob, bmask, scal, rowstart);
  k_scanA<<<dim3(NCC_, B_), dim3(256), 0, stream>>>(hidden, scal, rowstart,
                                                    stateL, cumA, carry, Achunk);
  k_scanB<<<dim3(64), dim3(64), 0, stream>>>(carry, Achunk);
  k_scanC<<<dim3(NCC_, B_), dim3(256), 0, stream>>>(stateL, cumA, rowstart,
                                                    carry, out);
}

// Round 11
// 69.086 us; speedup vs baseline: 1.3161x; 1.3161x over previous
//
#include <hip/hip_runtime.h>
#include <hip/hip_bf16.h>
#include <math.h>

// Problem constants (fixed by setup_inputs)
#define B_ 4
#define L_ 8192
#define M_ 4096
#define D_ 1024
#define CHUNK_ 32
#define NCC_ 128        // M_/CHUNK_
#define EPS_ 1e-4f

// clang native vector type for nontemporal builtins (same layout as float4)
typedef float f32x4 __attribute__((ext_vector_type(4)));

// Round-to-nearest-even f32 -> bf16 -> f32 (values are finite here)
__device__ __forceinline__ float bf16rf(float x) {
  unsigned u = __float_as_uint(x);
  u += 0x7FFFu + ((u >> 16) & 1u);
  u &= 0xFFFF0000u;
  return __uint_as_float(u);
}

// boundary_mask may arrive as bool8 (fmt 0), int32 (fmt 1), or float32 (fmt 2)
__device__ __forceinline__ bool mask_at(const void* mb, int fmt, int i) {
  if (fmt == 0) return ((const unsigned char*)mb)[i] != 0;
  if (fmt == 1) return ((const int*)mb)[i] != 0;
  return ((const float*)mb)[i] != 0.0f;
}

// Compute per-chunk scalars into LDS: s_scal[tid] = (a, c=dt*p, 1/dt, 0)
// for tid < CHUNK_. Deterministic -> identical values in scanA and scanC.
__device__ __forceinline__ void chunk_scal(const float* __restrict__ p_sorted,
                                           int b, int c, int tid,
                                           float4* s_scal) {
  if (tid < CHUNK_) {
    float p = p_sorted[b * M_ + c * CHUNK_ + tid];
    p = fminf(fmaxf(p, EPS_), 1.0f - EPS_);
    float dtf = bf16rf(logf(1.0f / (1.0f - p)));
    s_scal[tid] = make_float4(expf(-dtf), dtf * p, 1.0f / dtf, 0.0f);
  }
}

// prep: one 1024-thread block per batch. ONLY sorting work: mask dtype
// detect, wave-level prefix scan, scatter p into sorted order (global) and
// boundary rows into rowstart. No scal compute, no big LDS.
__global__ void __launch_bounds__(1024)
k_prep(const float* __restrict__ bprob,
       const void* __restrict__ bmask,
       float* __restrict__ p_sorted,
       int* __restrict__ rowstart) {
  const int b = blockIdx.x;
  const int tid = threadIdx.x;  // 0..1023
  const int lane = tid & 63, wid = tid >> 6;
  __shared__ int s_flags[2];
  __shared__ int s_wsum[17];

  if (tid < 2) s_flags[tid] = 0;
  __syncthreads();
  {
    const unsigned* mw = (const unsigned*)bmask;
    unsigned f0 = 0, f1 = 0;
    for (int i = tid; i < 8192; i += 1024) {
      unsigned v = mw[i];
      f0 |= v & 0xFFu;    // byte0: nonzero for u8 and i32, zero for f32
      f1 |= v & 0xFF00u;  // byte1: nonzero only for u8 (45% density)
    }
    if (f1) s_flags[0] = 1;
    if (f0) s_flags[1] = 1;
  }
  __syncthreads();
  const int fmt = s_flags[0] ? 0 : (s_flags[1] ? 1 : 2);

  // 8 contiguous tokens per thread
  const int base_l = tid * (L_ / 1024);
  bool mloc[L_ / 1024];
  int cnt = 0;
#pragma unroll
  for (int j = 0; j < L_ / 1024; ++j) {
    mloc[j] = mask_at(bmask, fmt, b * L_ + base_l + j);
    cnt += mloc[j] ? 1 : 0;
  }
  // wave-level inclusive scan of cnt (wave = 64 on gfx950)
  int incl = cnt;
#pragma unroll
  for (int off = 1; off < 64; off <<= 1) {
    int t = __shfl_up(incl, off);
    if (lane >= off) incl += t;
  }
  if (lane == 63) s_wsum[wid] = incl;
  __syncthreads();
  if (tid == 0) {
    int acc = 0;
#pragma unroll
    for (int w = 0; w < 16; ++w) { int t = s_wsum[w]; s_wsum[w] = acc; acc += t; }
    s_wsum[16] = acc;
  }
  // rowstart defaults while the scan finishes (independent)
  for (int r = tid; r <= M_; r += 1024) rowstart[b * (M_ + 1) + r] = L_;
  __syncthreads();
  const int excl = s_wsum[wid] + incl - cnt;
  const int nb = s_wsum[16];

  int run = excl;
#pragma unroll
  for (int j = 0; j < L_ / 1024; ++j) {
    int l = base_l + j;
    bool mb = mloc[j];
    int pos = mb ? run : (nb + (l - run));
    run += mb ? 1 : 0;
    if (pos < M_) {
      p_sorted[b * M_ + pos] = bprob[((size_t)(b * L_ + l)) * 2 + 1];
      if (mb) rowstart[b * (M_ + 1) + pos] = l;
    }
  }
}

// Pass A: per-(batch,chunk) local scan with zero carry-in; emit chunk-end
// partial state (carry) and chunk decay product (Achunk). scal recomputed
// in LDS from p_sorted.
__global__ void __launch_bounds__(256)
k_scanA(const float* __restrict__ hidden,
        const float* __restrict__ p_sorted,
        const int* __restrict__ rowstart,
        float* __restrict__ carry,     // [B][NCC][D]
        float* __restrict__ Achunk) {  // [B][NCC]
  const int c = blockIdx.x, b = blockIdx.y;
  const int tid = threadIdx.x;
  if (rowstart[b * (M_ + 1) + c * CHUNK_] >= L_) return;  // inactive chunk
  __shared__ float4 s_scal[CHUNK_];
  chunk_scal(p_sorted, b, c, tid, s_scal);
  __syncthreads();
  if (tid == 0) {
    float cp = 1.0f;
#pragma unroll
    for (int m = 0; m < CHUNK_; ++m) cp *= s_scal[m].x;
    Achunk[b * NCC_ + c] = cp;
  }
  const int d4 = tid * 4;
  const float* __restrict__ hp =
      hidden + ((size_t)(b * M_ + c * CHUNK_)) * D_ + d4;
  float hx = 0.f, hy = 0.f, hz = 0.f, hw = 0.f;
#pragma unroll
  for (int m = 0; m < CHUNK_; ++m) {
    const float4 s = s_scal[m];                 // a, c=dt*p, 1/dt
    const float4 x = *(const float4*)(hp + (size_t)m * D_);
    hx = fmaf(s.x, hx, s.y * bf16rf(x.x * s.z));
    hy = fmaf(s.x, hy, s.y * bf16rf(x.y * s.z));
    hz = fmaf(s.x, hz, s.y * bf16rf(x.z * s.z));
    hw = fmaf(s.x, hw, s.y * bf16rf(x.w * s.z));
  }
  *(float4*)(carry + ((size_t)(b * NCC_ + c)) * D_ + d4) =
      make_float4(hx, hy, hz, hw);
}

// Pass B: in-place inclusive scan across chunks (batch-16 loads: one
// latency per 16 chunks). 4096 independent (b,d) chains.
__global__ void __launch_bounds__(64)
k_scanB(float* __restrict__ carry, const float* __restrict__ Achunk) {
  const int chain = blockIdx.x * 64 + threadIdx.x;  // 0..4095
  const int bb = chain >> 10, dd = chain & 1023;
  const float* __restrict__ Ab = Achunk + bb * NCC_;
  float S = 0.0f;
  for (int g = 0; g < NCC_ / 16; ++g) {
    float v[16], A[16];
#pragma unroll
    for (int j = 0; j < 16; ++j)
      v[j] = carry[((size_t)(bb * NCC_ + g * 16 + j)) * D_ + dd];
#pragma unroll
    for (int j = 0; j < 16; ++j) A[j] = Ab[g * 16 + j];
#pragma unroll
    for (int j = 0; j < 16; ++j) { S = fmaf(A[j], S, v[j]); v[j] = S; }
#pragma unroll
    for (int j = 0; j < 16; ++j)
      carry[((size_t)(bb * NCC_ + g * 16 + j)) * D_ + dd] = v[j];
  }
}

// Pass C: read exclusive-carry vector (issued early, hidden under the LDS
// phase), local rescan of hidden with true carry-in, fused token scatter
// with nontemporal stores (out is write-once, never re-read).
__global__ void __launch_bounds__(256)
k_scanC(const float* __restrict__ hidden,
        const float* __restrict__ p_sorted,
        const int* __restrict__ rowstart,
        const float* __restrict__ carry,
        float* __restrict__ out) {
  const int c = blockIdx.x, b = blockIdx.y;
  const int tid = threadIdx.x;
  const int d4 = tid * 4;
  __shared__ float4 s_scal[CHUNK_];
  __shared__ int    s_rs[CHUNK_ + 1];

  // issue carry-in load first so it overlaps the LDS/scal phase
  float hx = 0.f, hy = 0.f, hz = 0.f, hw = 0.f;
  if (c > 0) {
    const float4 ci =
        *(const float4*)(carry + ((size_t)(b * NCC_ + c - 1)) * D_ + d4);
    hx = ci.x; hy = ci.y; hz = ci.z; hw = ci.w;
  }
  chunk_scal(p_sorted, b, c, tid, s_scal);
  if (tid <= CHUNK_) s_rs[tid] = rowstart[b * (M_ + 1) + c * CHUNK_ + tid];
  __syncthreads();
  if (s_rs[0] >= L_) return;                    // inactive chunk

  const float* __restrict__ hp =
      hidden + ((size_t)(b * M_ + c * CHUNK_)) * D_ + d4;
#pragma unroll
  for (int m = 0; m < CHUNK_; ++m) {
    const float4 s = s_scal[m];
    const float4 x = *(const float4*)(hp + (size_t)m * D_);
    hx = fmaf(s.x, hx, s.y * bf16rf(x.x * s.z));
    hy = fmaf(s.x, hy, s.y * bf16rf(x.y * s.z));
    hz = fmaf(s.x, hz, s.y * bf16rf(x.z * s.z));
    hw = fmaf(s.x, hw, s.y * bf16rf(x.w * s.z));
    const int r0 = s_rs[m], r1 = s_rs[m + 1];
    if (r1 > r0) {
      f32x4 o;
      o.x = bf16rf(hx); o.y = bf16rf(hy);
      o.z = bf16rf(hz); o.w = bf16rf(hw);
      for (int l = r0; l < r1; ++l)
        __builtin_nontemporal_store(
            o, (f32x4*)(out + ((size_t)(b * L_ + l)) * D_ + d4));
    }
  }
}

extern "C" void kernel_launch(void* const* d_in, const int* in_sizes, int n_in,
                              void* d_out, int out_size, void* d_ws, size_t ws_size,
                              hipStream_t stream) {
  const float* hidden = (const float*)d_in[0];
  const float* bprob  = (const float*)d_in[1];
  const void*  bmask  = d_in[2];
  float* out = (float*)d_out;

  float* p_sorted = (float*)d_ws;                            // B*M
  float* carry    = p_sorted + B_ * M_;                      // B*NCC*D
  float* Achunk   = carry + (size_t)B_ * NCC_ * D_;          // B*NCC
  int*   rowstart = (int*)(Achunk + B_ * NCC_);              // B*(M+1)

  k_prep<<<dim3(B_), dim3(1024), 0, stream>>>(bprob, bmask, p_sorted, rowstart);
  k_scanA<<<dim3(NCC_, B_), dim3(256), 0, stream>>>(hidden, p_sorted, rowstart,
                                                    carry, Achunk);
  k_scanB<<<dim3(64), dim3(64), 0, stream>>>(carry, Achunk);
  k_scanC<<<dim3(NCC_, B_), dim3(256), 0, stream>>>(hidden, p_sorted, rowstart,
                                                    carry, out);
}